// Round 3
// baseline (1112130.957 us; speedup 1.0000x reference)
//
#include <hip/hip_runtime.h>

// Seq2SeqWithAlignment: enc/dec LSTM -> hpre -> logits logsumexp -> Viterbi align.
// K=64 enc steps, T=128 dec tokens (127 dec steps used), H=512, E=100, V=32000.

#define K_ENC 64
#define HID   512
#define EMB   100
#define VOC   32000
#define G4    2048   // 4*HID

typedef __attribute__((ext_vector_type(8))) short  short8;
typedef __attribute__((ext_vector_type(4))) float  f32x4;
typedef unsigned long long u64;

#define LOG2E 1.4426950408889634f
#define LN2   0.6931471805599453f

__device__ __forceinline__ unsigned short f2bf(float f) {
  union { float f; unsigned u; } x; x.f = f;
  unsigned r = x.u + 0x7FFFu + ((x.u >> 16) & 1u);  // RNE
  return (unsigned short)(r >> 16);
}

__device__ __forceinline__ float fast_sigmoid(float x) {
  return __builtin_amdgcn_rcpf(1.f + __builtin_amdgcn_exp2f(-LOG2E * x));
}
__device__ __forceinline__ float fast_tanh(float x) {
  return 1.f - 2.f * __builtin_amdgcn_rcpf(1.f + __builtin_amdgcn_exp2f(2.f * LOG2E * x));
}

// ---------------- workspace layout (float offsets) ----------------
// OFF_PAD (0..255) repurposed as the sync scratch area (zeroed by kZero):
//   int   sync[0..7]  : per-XCD ticket counters
//   int   sync[8..9]  : per-group consensus words (lo16 arrived, hi16 ok-count)
//   u64   probe[64]   : at float offset 16 (startup fast-path probe words)
#define OFF_PAD   0
#define OFF_HBUF  256       // 4096 floats = 2048 u64: tagged h channels [grp][slot][512]
#define OFF_G0E   4352      // 64*2048  : enc Wih@x + bih + bhh
#define OFF_G0D   135424    // 127*2048 : dec
#define OFF_EENC  395520    // 64*512
#define OFF_D     428288    // 127*512
#define OFF_EWE   493312    // 64*100   : log2e * Eenc@We_E^T
#define OFF_DWD   499712    // 127*100  : log2e * (D@We_D^T + beh)
#define OFF_BEM   512412    // 32000    : log2e * bem
#define OFF_SUM   544412    // 127*64   : sum of 2^s over v (atomic)
#define OFF_EM    552540    // 127*64   : emission
#define OFF_WEM   560668    // ushort[4096000]: Wem bf16 in MFMA-B fragment-linear layout
// total ~10.4 MB

// ---------------- zero init (sync area, tagged h channels, sumexp) ----------------
__global__ void kZero(float* __restrict__ ws) {
  int gid = blockIdx.x * 256 + threadIdx.x;
  if (gid < 4352) ws[gid] = 0.f;                         // sync scratch + hbuf
  else if (gid < 4352 + 127 * 64) ws[OFF_SUM + gid - 4352] = 0.f;
}

// ---------------- G0 = Wih @ emb[tok] + bih + bhh ----------------
__global__ __launch_bounds__(256) void kG0(const int* __restrict__ x, const int* __restrict__ y,
                    const float* __restrict__ emb,
                    const float* __restrict__ eWih, const float* __restrict__ ebih,
                    const float* __restrict__ ebhh,
                    const float* __restrict__ dWih, const float* __restrict__ dbih,
                    const float* __restrict__ dbhh,
                    float* __restrict__ ws) {
  int gid = blockIdx.x * 256 + threadIdx.x;
  const int enc_total = K_ENC * G4;
  if (gid >= enc_total + 127 * G4) return;
  bool enc = gid < enc_total;
  int loc = enc ? gid : gid - enc_total;
  int t = loc >> 11, r = loc & (G4 - 1);
  int tok = enc ? x[t] : y[t];
  const float* Wr = (enc ? eWih : dWih) + r * EMB;
  const float* er = emb + tok * EMB;
  float s = 0.f;
  #pragma unroll 4
  for (int e = 0; e < EMB; ++e) s += er[e] * Wr[e];
  s += enc ? (ebih[r] + ebhh[r]) : (dbih[r] + dbhh[r]);
  ws[(enc ? OFF_G0E : OFF_G0D) + t * G4 + r] = s;
}

// ---------------- Wem -> bf16 MFMA-B fragment-linear layout, bem scaled ----------------
// block (vt,kb) = 1KB: lane L holds Wem[vt*16+(L&15)][kb*32+(L>>4)*8+j], j=0..7 (0-pad k>=100)
__global__ __launch_bounds__(256) void kWemPrep(const float* __restrict__ Wem,
                                               const float* __restrict__ bem,
                                               float* __restrict__ ws) {
  int gid = blockIdx.x * 256 + threadIdx.x;   // < 4096000
  int vt = gid >> 11;
  int kb = (gid >> 9) & 3;
  int L  = (gid >> 3) & 63;
  int j  = gid & 7;
  int v = vt * 16 + (L & 15);
  int k = kb * 32 + ((L >> 4) << 3) + j;
  float val = (k < EMB) ? Wem[v * EMB + k] : 0.f;
  ((unsigned short*)(ws + OFF_WEM))[gid] = f2bf(val);
  if (gid < VOC) ws[OFF_BEM + gid] = bem[gid] * LOG2E;
}

// ---------------- XCD-local atomic helpers ----------------
// Workgroup-scope RMW on a global address emits global_atomic with no sc bits ->
// executed at the issuing XCD's L2. Coherent among WGs co-located on that XCD;
// NOT cross-XCD coherent (hence the ticket-based co-location + startup consensus).
__device__ __forceinline__ u64 rmw_read_wg(u64* p) {
  return __hip_atomic_fetch_or(p, 0ULL, __ATOMIC_RELAXED, __HIP_MEMORY_SCOPE_WORKGROUP);
}
__device__ __forceinline__ void pub_wg(u64* p, u64 v) {
  (void)__hip_atomic_exchange(p, v, __ATOMIC_RELAXED, __HIP_MEMORY_SCOPE_WORKGROUP);
}

// ---------------- persistent LSTM, XCD-co-located groups ----------------
// R6 design:
//  * 1024 WGs launched; each reads HW_REG_XCC_ID. XCD0 WGs claim dec roles 0-31,
//    XCD1 WGs claim enc roles 0-31 (ticket counters); everyone else exits.
//    Each group therefore lives entirely on ONE XCD (32 WGs <= 32 CUs/XCD).
//  * Sync via tagged 64-bit words (tag<<32 | f32bits) as before, but with
//    XCD-L2-local (workgroup-scope) RMWs instead of MALL (device-scope) ones:
//    ~150-300cy round-trip instead of cross-die. A bounded startup probe +
//    single-word consensus per group verifies the fast path actually works;
//    on failure the whole group falls back to the proven device-scope path.
//  * R6 compile fix: no asm-pinning of the weight slice (backend rejects tied
//    indirect operands). Instead ALL pointer params are __restrict__ so the
//    loop's atomics/stores provably don't alias Whh -> LICM can keep the
//    64-VGPR weight slice resident (R5's VGPR_Count=48 = forced per-step
//    reload, most likely an aliasing constraint, not an occupancy choice).
// Poll is BOUNDED: sync failure => finite wrong answer, not a harness-timeout hang.
#define FAST_GUARD 1024
#define STEP_GUARD 16384

__global__ __launch_bounds__(512, 2) void kLstm(const float* __restrict__ eWhh,
                                                const float* __restrict__ dWhh,
                                                float* __restrict__ ws) {
  __shared__ int role_s;
  __shared__ int mode_s;
  int* syncI = (int*)ws;                    // tickets [0..7], consensus [8..9]
  u64* probe = (u64*)(ws + 16);             // 64 probe words
  const int tid = threadIdx.x;

  // ---- self-organize onto one XCD per group ----
  if (tid == 0) {
    int xcc;
    asm volatile("s_getreg_b32 %0, hwreg(HW_REG_XCC_ID)" : "=s"(xcc));
    xcc &= 7;
    int r = -1;
    if (xcc < 2) {
      int tkt = atomicAdd(&syncI[xcc], 1);  // device scope; once per WG
      if (tkt < 32) r = xcc * 32 + tkt;
    }
    role_s = r;
  }
  __syncthreads();
  const int role = role_s;
  if (role < 0) return;
  const int grp = (role < 32) ? 1 : 0;      // XCD0 -> dec (critical path), XCD1 -> enc
  const int wg  = role & 31;

  // ---- startup probe + per-group consensus: FAST (XCD-L2) vs SLOW (MALL) ----
  if (tid == 0) {
    u64* gprobe = probe + (role & 32);
    const u64 hi = 0xA5A5ULL << 32;
    pub_wg(&gprobe[wg], hi | (unsigned)(wg + 1));
    unsigned seen = 0;
    for (int it = 0; it < FAST_GUARD && seen != 0xFFFFFFFFu; ++it) {
      #pragma unroll
      for (int i = 0; i < 32; ++i) if (!(seen & (1u << i))) {
        u64 v = rmw_read_wg(&gprobe[i]);
        if (v == (hi | (unsigned)(i + 1))) seen |= (1u << i);
      }
      if (seen != 0xFFFFFFFFu) __builtin_amdgcn_s_sleep(8);
    }
    int ok = (seen == 0xFFFFFFFFu) ? 1 : 0;
    // single-word consensus: lo16 = arrived count, hi16 = ok count (device scope)
    atomicAdd(&syncI[8 + grp], 1 + (ok << 16));
    int combo = 0;
    for (int it = 0; it < 60000; ++it) {
      combo = atomicOr(&syncI[8 + grp], 0);
      if ((combo & 0xFFFF) >= 32) break;
      __builtin_amdgcn_s_sleep(8);
    }
    mode_s = ((combo >> 16) == 32) ? 1 : 0;
  }
  __syncthreads();
  const int fast = mode_s;

  const float* __restrict__ Whh = grp ? dWhh : eWhh;
  const float* __restrict__ G0  = ws + (grp ? OFF_G0D : OFF_G0E);
  float* hs = ws + (grp ? OFF_D : OFF_EENC);
  u64* hb = (u64*)(ws + OFF_HBUF) + grp * 1024;   // [2][512] tagged words
  const int steps = grp ? 127 : K_ENC;
  const int jl = tid >> 5, sub = tid & 31;
  const int j = wg * 16 + jl;                     // owned h index
  __shared__ float h_lds[32 * 20];                // [sub][16] padded to 20 (bank spread)

  // per-thread weight slice: 4 gates x 16 k (rows g*512+j, cols sub*16..+16) = 64 VGPRs
  float4 w4[16];
  #pragma unroll
  for (int g = 0; g < 4; ++g)
    #pragma unroll
    for (int q = 0; q < 4; ++q)
      w4[g * 4 + q] = *(const float4*)&Whh[(g * HID + j) * HID + sub * 16 + q * 4];

  float cst = 0.f;
  for (int t = 0; t < steps; ++t) {
    // G0 loads are h-independent: issue before the poll so they overlap it
    float g0i = G0[t * G4 + j];
    float g0f = G0[t * G4 + HID + j];
    float g0g = G0[t * G4 + 2 * HID + j];
    float g0o = G0[t * G4 + 3 * HID + j];
    // ---- wave 0: poll all 512 tagged words (8 per lane), per-word early-out ----
    if (tid < 64) {
      u64* src = hb + (t & 1) * 512 + tid * 8;
      const unsigned tag = (unsigned)t;
      u64 vv[8];
      bool fr[8];
      #pragma unroll
      for (int i = 0; i < 8; ++i) fr[i] = false;
      int guard = 0;
      for (;;) {
        bool ok = true;
        if (fast) {
          #pragma unroll
          for (int i = 0; i < 8; ++i) if (!fr[i]) vv[i] = rmw_read_wg(&src[i]);
        } else {
          #pragma unroll
          for (int i = 0; i < 8; ++i) if (!fr[i]) vv[i] = atomicOr(&src[i], 0ULL);
        }
        #pragma unroll
        for (int i = 0; i < 8; ++i) { fr[i] = fr[i] | ((unsigned)(vv[i] >> 32) == tag); ok &= fr[i]; }
        if (__all(ok) || ++guard >= STEP_GUARD) break;
        __builtin_amdgcn_s_sleep(1);
      }
      #pragma unroll
      for (int i = 0; i < 8; ++i) {
        int k = tid * 8 + i;
        union { unsigned u; float f; } c; c.u = (unsigned)vv[i];
        h_lds[(k >> 4) * 20 + (k & 15)] = c.f;
      }
    }
    __syncthreads();
    float h[16];
    #pragma unroll
    for (int kk = 0; kk < 16; ++kk) h[kk] = h_lds[sub * 20 + kk];
    float p0 = 0.f, p1 = 0.f, p2 = 0.f, p3 = 0.f;
    #pragma unroll
    for (int q = 0; q < 4; ++q) {
      p0 += w4[0+q].x*h[q*4+0] + w4[0+q].y*h[q*4+1] + w4[0+q].z*h[q*4+2] + w4[0+q].w*h[q*4+3];
      p1 += w4[4+q].x*h[q*4+0] + w4[4+q].y*h[q*4+1] + w4[4+q].z*h[q*4+2] + w4[4+q].w*h[q*4+3];
      p2 += w4[8+q].x*h[q*4+0] + w4[8+q].y*h[q*4+1] + w4[8+q].z*h[q*4+2] + w4[8+q].w*h[q*4+3];
      p3 += w4[12+q].x*h[q*4+0] + w4[12+q].y*h[q*4+1] + w4[12+q].z*h[q*4+2] + w4[12+q].w*h[q*4+3];
    }
    #pragma unroll
    for (int d = 1; d <= 16; d <<= 1) {       // reduce over 32 sub-lanes (stays in 32-half)
      p0 += __shfl_xor(p0, d); p1 += __shfl_xor(p1, d);
      p2 += __shfl_xor(p2, d); p3 += __shfl_xor(p3, d);
    }
    float si = fast_sigmoid(g0i + p0);
    float sf = fast_sigmoid(g0f + p1);
    float gG = fast_tanh(g0g + p2);
    float so = fast_sigmoid(g0o + p3);
    cst = sf * cst + si * gG;
    float hn = so * fast_tanh(cst);
    if (sub == 0) {
      union { float f; unsigned u; } hu; hu.f = hn;
      u64 pack = ((u64)((unsigned)t + 1u) << 32) | (u64)hu.u;
      u64* dst = &hb[((t + 1) & 1) * 512 + j];
      if (fast) pub_wg(dst, pack);            // XCD-L2 publish (~150cy ack)
      else atomicExch(dst, pack);             // MALL publish (fallback)
      hs[t * HID + j] = hn;
    }
  }
}

// ---------------- EWe_s / DWd_s projections (scaled by log2e) ----------------
__global__ __launch_bounds__(256) void kProj(const float* __restrict__ Weh,
                                             const float* __restrict__ beh,
                                             float* __restrict__ ws) {
  int bid = blockIdx.x;                 // 0..190
  bool enc = bid < K_ENC;
  int row = enc ? bid : bid - K_ENC;
  const float* in = ws + (enc ? OFF_EENC : OFF_D) + row * HID;
  __shared__ float sin_[HID];
  int tid = threadIdx.x;
  sin_[tid] = in[tid]; sin_[tid + 256] = in[tid + 256];
  __syncthreads();
  if (tid < EMB) {
    const float* wr = Weh + tid * 1024 + (enc ? 0 : HID);
    float s = 0.f;
    #pragma unroll 4
    for (int h = 0; h < HID; ++h) s += sin_[h] * wr[h];
    if (!enc) s += beh[tid];
    ws[(enc ? OFF_EWE : OFF_DWD) + row * EMB + tid] = s * LOG2E;
  }
}

// ---------------- fused logits GEMM (bf16 MFMA) + online sum(2^s) ----------------
__global__ __launch_bounds__(256) void kLogits(float* __restrict__ ws) {
  const int t = blockIdx.x >> 2;
  const int chunk = blockIdx.x & 3;
  const int tid = threadIdx.x;
  const int lane = tid & 63;
  const int wv = tid >> 6;
  const int quad = lane >> 4, l15 = lane & 15;
  __shared__ __align__(16) unsigned short A[64 * 128];   // hpre_s bf16, [m][k] k-padded to 128
  const float* EWe = ws + OFF_EWE;
  const float* DWd = ws + OFF_DWD + t * EMB;
  for (int idx = tid; idx < 64 * 128; idx += 256) {
    int m = idx >> 7, k = idx & 127;
    float hv = 0.f;
    if (k < EMB) { float s = EWe[m * EMB + k] + DWd[k]; hv = s > 0.f ? s : 0.f; }
    A[idx] = f2bf(hv);
  }
  __syncthreads();
  short8 af[4][4];   // A fragments persistent in VGPRs: [mtile][kblock]
  #pragma unroll
  for (int mt = 0; mt < 4; ++mt)
    #pragma unroll
    for (int kb = 0; kb < 4; ++kb)
      af[mt][kb] = *(const short8*)&A[(mt * 16 + l15) * 128 + kb * 32 + quad * 8];
  const unsigned short* wem = (const unsigned short*)(ws + OFF_WEM);
  const float* bem_s = ws + OFF_BEM;
  float rs[4][4];
  #pragma unroll
  for (int a = 0; a < 4; ++a)
    #pragma unroll
    for (int b = 0; b < 4; ++b) rs[a][b] = 0.f;
  int vt = chunk * 500 + wv;
  short8 nb0, nb1, nb2, nb3; float nbi;
  nb0 = *(const short8*)&wem[(vt * 4 + 0) * 512 + lane * 8];
  nb1 = *(const short8*)&wem[(vt * 4 + 1) * 512 + lane * 8];
  nb2 = *(const short8*)&wem[(vt * 4 + 2) * 512 + lane * 8];
  nb3 = *(const short8*)&wem[(vt * 4 + 3) * 512 + lane * 8];
  nbi = bem_s[vt * 16 + l15];
  for (int ii = wv; ii < 500; ii += 4) {
    short8 cb0 = nb0, cb1 = nb1, cb2 = nb2, cb3 = nb3;
    float cbi = nbi;
    int nvt = vt + 4;
    if (ii + 4 < 500) {   // software pipeline next B tile
      nb0 = *(const short8*)&wem[(nvt * 4 + 0) * 512 + lane * 8];
      nb1 = *(const short8*)&wem[(nvt * 4 + 1) * 512 + lane * 8];
      nb2 = *(const short8*)&wem[(nvt * 4 + 2) * 512 + lane * 8];
      nb3 = *(const short8*)&wem[(nvt * 4 + 3) * 512 + lane * 8];
      nbi = bem_s[nvt * 16 + l15];
    }
    f32x4 acc[4];
    #pragma unroll
    for (int mt = 0; mt < 4; ++mt) acc[mt] = (f32x4){cbi, cbi, cbi, cbi};  // init with bem
    #pragma unroll
    for (int mt = 0; mt < 4; ++mt) {
      acc[mt] = __builtin_amdgcn_mfma_f32_16x16x32_bf16(af[mt][0], cb0, acc[mt], 0, 0, 0);
      acc[mt] = __builtin_amdgcn_mfma_f32_16x16x32_bf16(af[mt][1], cb1, acc[mt], 0, 0, 0);
      acc[mt] = __builtin_amdgcn_mfma_f32_16x16x32_bf16(af[mt][2], cb2, acc[mt], 0, 0, 0);
      acc[mt] = __builtin_amdgcn_mfma_f32_16x16x32_bf16(af[mt][3], cb3, acc[mt], 0, 0, 0);
    }
    #pragma unroll
    for (int mt = 0; mt < 4; ++mt)
      #pragma unroll
      for (int r = 0; r < 4; ++r)
        rs[mt][r] += __builtin_amdgcn_exp2f(acc[mt][r]);   // s already includes log2e scale
    vt = nvt;
  }
  // reduce across the 16 column-lanes of each quad, then one atomic per row
  #pragma unroll
  for (int d = 1; d < 16; d <<= 1)
    #pragma unroll
    for (int mt = 0; mt < 4; ++mt)
      #pragma unroll
      for (int r = 0; r < 4; ++r)
        rs[mt][r] += __shfl_xor(rs[mt][r], d);
  if (l15 == 0) {
    float* sum = ws + OFF_SUM + t * 64;
    #pragma unroll
    for (int mt = 0; mt < 4; ++mt)
      #pragma unroll
      for (int r = 0; r < 4; ++r)
        atomicAdd(&sum[mt * 16 + quad * 4 + r], rs[mt][r]);
  }
}

// ---------------- emission = ln2 * (s_word - log2(sum 2^s)), s_word in fp32 ----------------
__global__ __launch_bounds__(256) void kEmission(const int* __restrict__ y,
                                                 const float* __restrict__ Wem,
                                                 float* __restrict__ ws) {
  int gid = blockIdx.x * 256 + threadIdx.x;
  if (gid >= 127 * 64) return;
  int t = gid >> 6, m = gid & 63;
  const float* ew = ws + OFF_EWE + m * EMB;
  const float* dw = ws + OFF_DWD + t * EMB;
  int wt = y[t + 1];
  const float* wr = Wem + wt * EMB;
  float s = ws[OFF_BEM + wt];
  #pragma unroll 4
  for (int e = 0; e < EMB; ++e) {
    float h = ew[e] + dw[e];
    h = h > 0.f ? h : 0.f;
    s += h * wr[e];
  }
  ws[OFF_EM + gid] = LN2 * (s - __builtin_amdgcn_logf(ws[OFF_SUM + gid]));
}

// ---------------- Viterbi: prefix-max trick + backtrace ----------------
// tranm[i][j] = fe + fs*(63-i-j) (i+j<64). scores[i][j] = q[i] + fe + fs*(63-j), q[i]=pa[i]-fs*i.
// flip cancels: new_pa[j] = P[j] + fe + fs*j + em[t][j]; ind'[j] = argP[j]  (P = prefix max of q).
__global__ __launch_bounds__(256) void kViterbi(const float* __restrict__ ws, float* __restrict__ out) {
  __shared__ float em_lds[127 * 64];
  __shared__ int   inds[128 * 64];
  __shared__ float sval;
  const int tid = threadIdx.x;
  for (int i = tid; i < 127 * 64; i += 256) em_lds[i] = ws[OFF_EM + i];
  if (tid < 64) inds[tid] = 0;   // indices row 0
  __syncthreads();
  if (tid < 64) {
    const int j = tid;
    const float fs = -0.4054651081081644f;   // log(128/192)
    const float fe = -1.0986122886681098f;   // log(64/192)
    float pa = 0.f;
    float emnext = em_lds[j];
    for (int t = 0; t < 127; ++t) {
      float emc = emnext;
      if (t < 126) emnext = em_lds[(t + 1) * 64 + j];
      float v = fmaf(-fs, (float)j, pa);   // q[j]
      int idx = j;
      #pragma unroll
      for (int d = 1; d < 64; d <<= 1) {   // inclusive prefix max, earliest argmax on ties
        float vv = __shfl_up(v, d);
        int   ii = __shfl_up(idx, d);
        bool cur = v > vv;                 // strict >: keep earlier index on ties
        v   = cur ? v : vv;
        idx = cur ? idx : ii;
      }
      pa = v + fe + fs * (float)j + emc;
      inds[(t + 1) * 64 + j] = idx;
    }
    if (j == 63) sval = pa;
  }
  __syncthreads();
  if (tid == 0) {
    int ind = 63;
    for (int t = 127; t >= 0; --t) {
      ind = inds[t * 64 + ind];
      out[t] = (float)ind;
    }
    out[128] = sval;
  }
}

extern "C" void kernel_launch(void* const* d_in, const int* in_sizes, int n_in,
                              void* d_out, int out_size, void* d_ws, size_t ws_size,
                              hipStream_t stream) {
  const int*   x    = (const int*)d_in[0];
  const int*   y    = (const int*)d_in[1];
  const float* emb  = (const float*)d_in[2];
  const float* eWih = (const float*)d_in[3];
  const float* eWhh = (const float*)d_in[4];
  const float* ebih = (const float*)d_in[5];
  const float* ebhh = (const float*)d_in[6];
  const float* dWih = (const float*)d_in[7];
  const float* dWhh = (const float*)d_in[8];
  const float* dbih = (const float*)d_in[9];
  const float* dbhh = (const float*)d_in[10];
  const float* Weh  = (const float*)d_in[11];
  const float* beh  = (const float*)d_in[12];
  const float* Wem  = (const float*)d_in[13];
  const float* bem  = (const float*)d_in[14];
  float* ws  = (float*)d_ws;
  float* out = (float*)d_out;

  hipLaunchKernelGGL(kZero,     dim3(49),    dim3(256), 0, stream, ws);
  hipLaunchKernelGGL(kG0,       dim3(1528),  dim3(256), 0, stream, x, y, emb, eWih, ebih, ebhh, dWih, dbih, dbhh, ws);
  hipLaunchKernelGGL(kWemPrep,  dim3(16000), dim3(256), 0, stream, Wem, bem, ws);
  hipLaunchKernelGGL(kLstm,     dim3(1024),  dim3(512), 0, stream, eWhh, dWhh, ws);
  hipLaunchKernelGGL(kProj,     dim3(191),   dim3(256), 0, stream, Weh, beh, ws);
  hipLaunchKernelGGL(kLogits,   dim3(508),   dim3(256), 0, stream, ws);
  hipLaunchKernelGGL(kEmission, dim3(32),    dim3(256), 0, stream, y, Wem, ws);
  hipLaunchKernelGGL(kViterbi,  dim3(1),     dim3(256), 0, stream, ws, out);
}

// Round 6
// 2351.649 us; speedup vs baseline: 472.9155x; 472.9155x over previous
//
#include <hip/hip_runtime.h>

// Seq2SeqWithAlignment: enc/dec LSTM -> hpre -> logits logsumexp -> Viterbi align.
// K=64 enc steps, T=128 dec tokens (127 dec steps used), H=512, E=100, V=32000.

#define K_ENC 64
#define HID   512
#define EMB   100
#define VOC   32000
#define G4    2048   // 4*HID

typedef __attribute__((ext_vector_type(8))) short  short8;
typedef __attribute__((ext_vector_type(4))) float  f32x4;
typedef unsigned long long u64;

#define LOG2E 1.4426950408889634f
#define LN2   0.6931471805599453f

__device__ __forceinline__ unsigned short f2bf(float f) {
  union { float f; unsigned u; } x; x.f = f;
  unsigned r = x.u + 0x7FFFu + ((x.u >> 16) & 1u);  // RNE
  return (unsigned short)(r >> 16);
}

__device__ __forceinline__ float fast_sigmoid(float x) {
  return __builtin_amdgcn_rcpf(1.f + __builtin_amdgcn_exp2f(-LOG2E * x));
}
__device__ __forceinline__ float fast_tanh(float x) {
  return 1.f - 2.f * __builtin_amdgcn_rcpf(1.f + __builtin_amdgcn_exp2f(2.f * LOG2E * x));
}

// ---------------- workspace layout (float offsets) ----------------
// OFF_PAD (0..255): sync scratch (zeroed by kZero):
//   int sync[0..7]: per-XCD ticket counters; sync[8..9]: consensus words
//   u64 probe[64] at float offset 16
#define OFF_PAD   0
#define OFF_HBUF  256       // 4096 floats = 2048 u64: tagged h channels [grp][slot][512]
#define OFF_G0E   4352      // 64*2048  : enc Wih@x + bih + bhh
#define OFF_G0D   135424    // 127*2048 : dec
#define OFF_EENC  395520    // 64*512
#define OFF_D     428288    // 127*512
#define OFF_EWE   493312    // 64*100   : log2e * Eenc@We_E^T
#define OFF_DWD   499712    // 127*100  : log2e * (D@We_D^T + beh)
#define OFF_BEM   512412    // 32000    : log2e * bem
#define OFF_SUM   544412    // 127*64   : sum of 2^s over v (atomic)
#define OFF_EM    552540    // 127*64   : emission
#define OFF_WEM   560668    // ushort[4096000]: Wem bf16 in MFMA-B fragment-linear layout
// total ~10.4 MB

// ---------------- zero init ----------------
__global__ void kZero(float* __restrict__ ws) {
  int gid = blockIdx.x * 256 + threadIdx.x;
  if (gid < 4352) ws[gid] = 0.f;                         // sync scratch + hbuf
  else if (gid < 4352 + 127 * 64) ws[OFF_SUM + gid - 4352] = 0.f;
}

// ---------------- G0 = Wih @ emb[tok] + bih + bhh ----------------
__global__ __launch_bounds__(256) void kG0(const int* __restrict__ x, const int* __restrict__ y,
                    const float* __restrict__ emb,
                    const float* __restrict__ eWih, const float* __restrict__ ebih,
                    const float* __restrict__ ebhh,
                    const float* __restrict__ dWih, const float* __restrict__ dbih,
                    const float* __restrict__ dbhh,
                    float* __restrict__ ws) {
  int gid = blockIdx.x * 256 + threadIdx.x;
  const int enc_total = K_ENC * G4;
  if (gid >= enc_total + 127 * G4) return;
  bool enc = gid < enc_total;
  int loc = enc ? gid : gid - enc_total;
  int t = loc >> 11, r = loc & (G4 - 1);
  int tok = enc ? x[t] : y[t];
  const float* Wr = (enc ? eWih : dWih) + r * EMB;
  const float* er = emb + tok * EMB;
  float s = 0.f;
  #pragma unroll 4
  for (int e = 0; e < EMB; ++e) s += er[e] * Wr[e];
  s += enc ? (ebih[r] + ebhh[r]) : (dbih[r] + dbhh[r]);
  ws[(enc ? OFF_G0E : OFF_G0D) + t * G4 + r] = s;
}

// ---------------- Wem -> bf16 MFMA-B fragment-linear layout, bem scaled ----------------
__global__ __launch_bounds__(256) void kWemPrep(const float* __restrict__ Wem,
                                               const float* __restrict__ bem,
                                               float* __restrict__ ws) {
  int gid = blockIdx.x * 256 + threadIdx.x;   // < 4096000
  int vt = gid >> 11;
  int kb = (gid >> 9) & 3;
  int L  = (gid >> 3) & 63;
  int j  = gid & 7;
  int v = vt * 16 + (L & 15);
  int k = kb * 32 + ((L >> 4) << 3) + j;
  float val = (k < EMB) ? Wem[v * EMB + k] : 0.f;
  ((unsigned short*)(ws + OFF_WEM))[gid] = f2bf(val);
  if (gid < VOC) ws[OFF_BEM + gid] = bem[gid] * LOG2E;
}

// ---------------- XCD-L2-local atomic helpers (inline asm) ----------------
// R7 lesson: __hip_atomic_fetch_or(p,0,WORKGROUP) is canonicalized by LLVM to an
// atomic LOAD; at workgroup scope that is a plain global_load served by the
// per-CU L1 -> the poll re-read its own STALE L1 line until eviction (~9ms/step,
// 1.18s total). Atomic RMWs architecturally bypass L1 and execute at the L2 of
// the issuing XCD when sc1 is NOT set (sc1 would force MALL = the old slow path).
// So: poll = global_atomic_or_x2 with 0 (sc0 = return old value), publish =
// global_atomic_swap_x2. Inline asm also can't be strength-reduced to a load.
__device__ __forceinline__ u64 aor1_l2(u64* p) {
  u64 r;
  asm volatile("global_atomic_or_x2 %0, %1, %2, off sc0\n\t"
               "s_waitcnt vmcnt(0)"
               : "=&v"(r) : "v"(p), "v"(0ULL) : "memory");
  return r;
}
__device__ __forceinline__ void aswap_l2(u64* p, u64 v) {
  asm volatile("global_atomic_swap_x2 %0, %1, off" : : "v"(p), "v"(v) : "memory");
}
// 8 RMW-reads at base+0..56B, single waitcnt => one L2 round-trip per poll iter.
__device__ __forceinline__ void aor8_l2(u64* base, u64& a0, u64& a1, u64& a2, u64& a3,
                                        u64& a4, u64& a5, u64& a6, u64& a7) {
  asm volatile(
    "global_atomic_or_x2 %0, %8, %9, off sc0\n\t"
    "global_atomic_or_x2 %1, %8, %9, off offset:8 sc0\n\t"
    "global_atomic_or_x2 %2, %8, %9, off offset:16 sc0\n\t"
    "global_atomic_or_x2 %3, %8, %9, off offset:24 sc0\n\t"
    "global_atomic_or_x2 %4, %8, %9, off offset:32 sc0\n\t"
    "global_atomic_or_x2 %5, %8, %9, off offset:40 sc0\n\t"
    "global_atomic_or_x2 %6, %8, %9, off offset:48 sc0\n\t"
    "global_atomic_or_x2 %7, %8, %9, off offset:56 sc0\n\t"
    "s_waitcnt vmcnt(0)"
    : "=&v"(a0), "=&v"(a1), "=&v"(a2), "=&v"(a3),
      "=&v"(a4), "=&v"(a5), "=&v"(a6), "=&v"(a7)
    : "v"(base), "v"(0ULL) : "memory");
}

// ---------------- persistent LSTM, XCD-co-located groups ----------------
//  * 1024 WGs; each reads HW_REG_XCC_ID. XCD0 WGs claim dec roles 0-31, XCD1 WGs
//    claim enc roles 0-31 (ticket counters); everyone else exits. Each group
//    lives entirely on ONE XCD (32 WGs <= 32 CUs/XCD).
//  * Sync via tagged 64-bit words (tag<<32 | f32bits) using the L2-local atomic
//    RMW helpers above. Startup probe (same mechanism) + consensus; on failure
//    the whole group falls back to the proven device-scope (MALL) path.
//  * The asm "memory" clobbers inside the step loop also forbid the compiler
//    from sinking the 64-VGPR weight-slice loads into the loop (R5: VGPR=48,
//    R7: VGPR=64 -> weights were being re-read every step).
// Poll is BOUNDED: sync failure => finite wrong answer, not a harness hang.
#define FAST_GUARD 1024
#define STEP_GUARD 16384

__global__ __launch_bounds__(512, 2) void kLstm(const float* __restrict__ eWhh,
                                                const float* __restrict__ dWhh,
                                                float* __restrict__ ws) {
  __shared__ int role_s;
  __shared__ int mode_s;
  int* syncI = (int*)ws;                    // tickets [0..7], consensus [8..9]
  u64* probe = (u64*)(ws + 16);             // 64 probe words
  const int tid = threadIdx.x;

  // ---- self-organize onto one XCD per group ----
  if (tid == 0) {
    int xcc;
    asm volatile("s_getreg_b32 %0, hwreg(HW_REG_XCC_ID)" : "=s"(xcc));
    xcc &= 7;
    int r = -1;
    if (xcc < 2) {
      int tkt = atomicAdd(&syncI[xcc], 1);  // device scope; once per WG
      if (tkt < 32) r = xcc * 32 + tkt;
    }
    role_s = r;
  }
  __syncthreads();
  const int role = role_s;
  if (role < 0) return;
  const int grp = (role < 32) ? 1 : 0;      // XCD0 -> dec (critical path), XCD1 -> enc
  const int wg  = role & 31;

  // ---- startup probe + per-group consensus: FAST (XCD-L2 atomics) vs SLOW (MALL) ----
  if (tid == 0) {
    u64* gprobe = probe + (role & 32);
    const u64 hi = 0xA5A5ULL << 32;
    aswap_l2(&gprobe[wg], hi | (unsigned)(wg + 1));
    unsigned seen = 0;
    for (int it = 0; it < FAST_GUARD && seen != 0xFFFFFFFFu; ++it) {
      for (int i = 0; i < 32; ++i) if (!(seen & (1u << i))) {
        u64 v = aor1_l2(&gprobe[i]);
        if (v == (hi | (unsigned)(i + 1))) seen |= (1u << i);
      }
      if (seen != 0xFFFFFFFFu) __builtin_amdgcn_s_sleep(8);
    }
    int ok = (seen == 0xFFFFFFFFu) ? 1 : 0;
    // single-word consensus: lo16 = arrived count, hi16 = ok count (device scope)
    atomicAdd(&syncI[8 + grp], 1 + (ok << 16));
    int combo = 0;
    for (int it = 0; it < 60000; ++it) {
      combo = atomicOr(&syncI[8 + grp], 0);
      if ((combo & 0xFFFF) >= 32) break;
      __builtin_amdgcn_s_sleep(8);
    }
    mode_s = ((combo >> 16) == 32) ? 1 : 0;
  }
  __syncthreads();
  const int fast = mode_s;

  const float* __restrict__ Whh = grp ? dWhh : eWhh;
  const float* __restrict__ G0  = ws + (grp ? OFF_G0D : OFF_G0E);
  float* hs = ws + (grp ? OFF_D : OFF_EENC);
  u64* hb = (u64*)(ws + OFF_HBUF) + grp * 1024;   // [2][512] tagged words
  const int steps = grp ? 127 : K_ENC;
  const int jl = tid >> 5, sub = tid & 31;
  const int j = wg * 16 + jl;                     // owned h index
  __shared__ float h_lds[32 * 20];                // [sub][16] padded to 20 (bank spread)

  // per-thread weight slice: 4 gates x 16 k (rows g*512+j, cols sub*16..+16) = 64 VGPRs
  float4 w4[16];
  #pragma unroll
  for (int g = 0; g < 4; ++g)
    #pragma unroll
    for (int q = 0; q < 4; ++q)
      w4[g * 4 + q] = *(const float4*)&Whh[(g * HID + j) * HID + sub * 16 + q * 4];

  float cst = 0.f;
  for (int t = 0; t < steps; ++t) {
    // G0 loads are h-independent: issue before the poll so they overlap it
    float g0i = G0[t * G4 + j];
    float g0f = G0[t * G4 + HID + j];
    float g0g = G0[t * G4 + 2 * HID + j];
    float g0o = G0[t * G4 + 3 * HID + j];
    // ---- wave 0: poll all 512 tagged words (8 per lane) ----
    if (tid < 64) {
      u64* src = hb + (t & 1) * 512 + tid * 8;
      const unsigned tag = (unsigned)t;
      u64 q0, q1, q2, q3, q4, q5, q6, q7;
      if (fast) {
        int guard = 0;
        for (;;) {
          aor8_l2(src, q0, q1, q2, q3, q4, q5, q6, q7);
          bool ok = ((unsigned)(q0 >> 32) == tag) && ((unsigned)(q1 >> 32) == tag)
                 && ((unsigned)(q2 >> 32) == tag) && ((unsigned)(q3 >> 32) == tag)
                 && ((unsigned)(q4 >> 32) == tag) && ((unsigned)(q5 >> 32) == tag)
                 && ((unsigned)(q6 >> 32) == tag) && ((unsigned)(q7 >> 32) == tag);
          if (__all(ok) || ++guard >= STEP_GUARD) break;
          __builtin_amdgcn_s_sleep(1);
        }
      } else {
        u64 vv[8];
        bool fr[8];
        #pragma unroll
        for (int i = 0; i < 8; ++i) fr[i] = false;
        int guard = 0;
        for (;;) {
          bool ok = true;
          #pragma unroll
          for (int i = 0; i < 8; ++i) if (!fr[i]) vv[i] = atomicOr(&src[i], 0ULL);
          #pragma unroll
          for (int i = 0; i < 8; ++i) { fr[i] = fr[i] | ((unsigned)(vv[i] >> 32) == tag); ok &= fr[i]; }
          if (__all(ok) || ++guard >= STEP_GUARD) break;
          __builtin_amdgcn_s_sleep(1);
        }
        q0 = vv[0]; q1 = vv[1]; q2 = vv[2]; q3 = vv[3];
        q4 = vv[4]; q5 = vv[5]; q6 = vv[6]; q7 = vv[7];
      }
      u64 qq[8] = {q0, q1, q2, q3, q4, q5, q6, q7};
      #pragma unroll
      for (int i = 0; i < 8; ++i) {
        int k = tid * 8 + i;
        union { unsigned u; float f; } c; c.u = (unsigned)qq[i];
        h_lds[(k >> 4) * 20 + (k & 15)] = c.f;
      }
    }
    __syncthreads();
    float h[16];
    #pragma unroll
    for (int kk = 0; kk < 16; ++kk) h[kk] = h_lds[sub * 20 + kk];
    float p0 = 0.f, p1 = 0.f, p2 = 0.f, p3 = 0.f;
    #pragma unroll
    for (int q = 0; q < 4; ++q) {
      p0 += w4[0+q].x*h[q*4+0] + w4[0+q].y*h[q*4+1] + w4[0+q].z*h[q*4+2] + w4[0+q].w*h[q*4+3];
      p1 += w4[4+q].x*h[q*4+0] + w4[4+q].y*h[q*4+1] + w4[4+q].z*h[q*4+2] + w4[4+q].w*h[q*4+3];
      p2 += w4[8+q].x*h[q*4+0] + w4[8+q].y*h[q*4+1] + w4[8+q].z*h[q*4+2] + w4[8+q].w*h[q*4+3];
      p3 += w4[12+q].x*h[q*4+0] + w4[12+q].y*h[q*4+1] + w4[12+q].z*h[q*4+2] + w4[12+q].w*h[q*4+3];
    }
    #pragma unroll
    for (int d = 1; d <= 16; d <<= 1) {       // reduce over 32 sub-lanes (stays in 32-half)
      p0 += __shfl_xor(p0, d); p1 += __shfl_xor(p1, d);
      p2 += __shfl_xor(p2, d); p3 += __shfl_xor(p3, d);
    }
    float si = fast_sigmoid(g0i + p0);
    float sf = fast_sigmoid(g0f + p1);
    float gG = fast_tanh(g0g + p2);
    float so = fast_sigmoid(g0o + p3);
    cst = sf * cst + si * gG;
    float hn = so * fast_tanh(cst);
    if (sub == 0) {
      union { float f; unsigned u; } hu; hu.f = hn;
      u64 pack = ((u64)((unsigned)t + 1u) << 32) | (u64)hu.u;
      u64* dst = &hb[((t + 1) & 1) * 512 + j];
      if (fast) aswap_l2(dst, pack);          // XCD-L2 publish
      else atomicExch(dst, pack);             // MALL publish (fallback)
      hs[t * HID + j] = hn;
    }
  }
}

// ---------------- EWe_s / DWd_s projections (scaled by log2e) ----------------
__global__ __launch_bounds__(256) void kProj(const float* __restrict__ Weh,
                                             const float* __restrict__ beh,
                                             float* __restrict__ ws) {
  int bid = blockIdx.x;                 // 0..190
  bool enc = bid < K_ENC;
  int row = enc ? bid : bid - K_ENC;
  const float* in = ws + (enc ? OFF_EENC : OFF_D) + row * HID;
  __shared__ float sin_[HID];
  int tid = threadIdx.x;
  sin_[tid] = in[tid]; sin_[tid + 256] = in[tid + 256];
  __syncthreads();
  if (tid < EMB) {
    const float* wr = Weh + tid * 1024 + (enc ? 0 : HID);
    float s = 0.f;
    #pragma unroll 4
    for (int h = 0; h < HID; ++h) s += sin_[h] * wr[h];
    if (!enc) s += beh[tid];
    ws[(enc ? OFF_EWE : OFF_DWD) + row * EMB + tid] = s * LOG2E;
  }
}

// ---------------- fused logits GEMM (bf16 MFMA) + online sum(2^s) ----------------
__global__ __launch_bounds__(256) void kLogits(float* __restrict__ ws) {
  const int t = blockIdx.x >> 2;
  const int chunk = blockIdx.x & 3;
  const int tid = threadIdx.x;
  const int lane = tid & 63;
  const int wv = tid >> 6;
  const int quad = lane >> 4, l15 = lane & 15;
  __shared__ __align__(16) unsigned short A[64 * 128];   // hpre_s bf16, [m][k] k-padded to 128
  const float* EWe = ws + OFF_EWE;
  const float* DWd = ws + OFF_DWD + t * EMB;
  for (int idx = tid; idx < 64 * 128; idx += 256) {
    int m = idx >> 7, k = idx & 127;
    float hv = 0.f;
    if (k < EMB) { float s = EWe[m * EMB + k] + DWd[k]; hv = s > 0.f ? s : 0.f; }
    A[idx] = f2bf(hv);
  }
  __syncthreads();
  short8 af[4][4];   // A fragments persistent in VGPRs: [mtile][kblock]
  #pragma unroll
  for (int mt = 0; mt < 4; ++mt)
    #pragma unroll
    for (int kb = 0; kb < 4; ++kb)
      af[mt][kb] = *(const short8*)&A[(mt * 16 + l15) * 128 + kb * 32 + quad * 8];
  const unsigned short* wem = (const unsigned short*)(ws + OFF_WEM);
  const float* bem_s = ws + OFF_BEM;
  float rs[4][4];
  #pragma unroll
  for (int a = 0; a < 4; ++a)
    #pragma unroll
    for (int b = 0; b < 4; ++b) rs[a][b] = 0.f;
  int vt = chunk * 500 + wv;
  short8 nb0, nb1, nb2, nb3; float nbi;
  nb0 = *(const short8*)&wem[(vt * 4 + 0) * 512 + lane * 8];
  nb1 = *(const short8*)&wem[(vt * 4 + 1) * 512 + lane * 8];
  nb2 = *(const short8*)&wem[(vt * 4 + 2) * 512 + lane * 8];
  nb3 = *(const short8*)&wem[(vt * 4 + 3) * 512 + lane * 8];
  nbi = bem_s[vt * 16 + l15];
  for (int ii = wv; ii < 500; ii += 4) {
    short8 cb0 = nb0, cb1 = nb1, cb2 = nb2, cb3 = nb3;
    float cbi = nbi;
    int nvt = vt + 4;
    if (ii + 4 < 500) {   // software pipeline next B tile
      nb0 = *(const short8*)&wem[(nvt * 4 + 0) * 512 + lane * 8];
      nb1 = *(const short8*)&wem[(nvt * 4 + 1) * 512 + lane * 8];
      nb2 = *(const short8*)&wem[(nvt * 4 + 2) * 512 + lane * 8];
      nb3 = *(const short8*)&wem[(nvt * 4 + 3) * 512 + lane * 8];
      nbi = bem_s[nvt * 16 + l15];
    }
    f32x4 acc[4];
    #pragma unroll
    for (int mt = 0; mt < 4; ++mt) acc[mt] = (f32x4){cbi, cbi, cbi, cbi};  // init with bem
    #pragma unroll
    for (int mt = 0; mt < 4; ++mt) {
      acc[mt] = __builtin_amdgcn_mfma_f32_16x16x32_bf16(af[mt][0], cb0, acc[mt], 0, 0, 0);
      acc[mt] = __builtin_amdgcn_mfma_f32_16x16x32_bf16(af[mt][1], cb1, acc[mt], 0, 0, 0);
      acc[mt] = __builtin_amdgcn_mfma_f32_16x16x32_bf16(af[mt][2], cb2, acc[mt], 0, 0, 0);
      acc[mt] = __builtin_amdgcn_mfma_f32_16x16x32_bf16(af[mt][3], cb3, acc[mt], 0, 0, 0);
    }
    #pragma unroll
    for (int mt = 0; mt < 4; ++mt)
      #pragma unroll
      for (int r = 0; r < 4; ++r)
        rs[mt][r] += __builtin_amdgcn_exp2f(acc[mt][r]);   // s already includes log2e scale
    vt = nvt;
  }
  // reduce across the 16 column-lanes of each quad, then one atomic per row
  #pragma unroll
  for (int d = 1; d < 16; d <<= 1)
    #pragma unroll
    for (int mt = 0; mt < 4; ++mt)
      #pragma unroll
      for (int r = 0; r < 4; ++r)
        rs[mt][r] += __shfl_xor(rs[mt][r], d);
  if (l15 == 0) {
    float* sum = ws + OFF_SUM + t * 64;
    #pragma unroll
    for (int mt = 0; mt < 4; ++mt)
      #pragma unroll
      for (int r = 0; r < 4; ++r)
        atomicAdd(&sum[mt * 16 + quad * 4 + r], rs[mt][r]);
  }
}

// ---------------- emission = ln2 * (s_word - log2(sum 2^s)), s_word in fp32 ----------------
__global__ __launch_bounds__(256) void kEmission(const int* __restrict__ y,
                                                 const float* __restrict__ Wem,
                                                 float* __restrict__ ws) {
  int gid = blockIdx.x * 256 + threadIdx.x;
  if (gid >= 127 * 64) return;
  int t = gid >> 6, m = gid & 63;
  const float* ew = ws + OFF_EWE + m * EMB;
  const float* dw = ws + OFF_DWD + t * EMB;
  int wt = y[t + 1];
  const float* wr = Wem + wt * EMB;
  float s = ws[OFF_BEM + wt];
  #pragma unroll 4
  for (int e = 0; e < EMB; ++e) {
    float h = ew[e] + dw[e];
    h = h > 0.f ? h : 0.f;
    s += h * wr[e];
  }
  ws[OFF_EM + gid] = LN2 * (s - __builtin_amdgcn_logf(ws[OFF_SUM + gid]));
}

// ---------------- Viterbi: prefix-max trick + backtrace ----------------
__global__ __launch_bounds__(256) void kViterbi(const float* __restrict__ ws, float* __restrict__ out) {
  __shared__ float em_lds[127 * 64];
  __shared__ int   inds[128 * 64];
  __shared__ float sval;
  const int tid = threadIdx.x;
  for (int i = tid; i < 127 * 64; i += 256) em_lds[i] = ws[OFF_EM + i];
  if (tid < 64) inds[tid] = 0;   // indices row 0
  __syncthreads();
  if (tid < 64) {
    const int j = tid;
    const float fs = -0.4054651081081644f;   // log(128/192)
    const float fe = -1.0986122886681098f;   // log(64/192)
    float pa = 0.f;
    float emnext = em_lds[j];
    for (int t = 0; t < 127; ++t) {
      float emc = emnext;
      if (t < 126) emnext = em_lds[(t + 1) * 64 + j];
      float v = fmaf(-fs, (float)j, pa);   // q[j]
      int idx = j;
      #pragma unroll
      for (int d = 1; d < 64; d <<= 1) {   // inclusive prefix max, earliest argmax on ties
        float vv = __shfl_up(v, d);
        int   ii = __shfl_up(idx, d);
        bool cur = v > vv;                 // strict >: keep earlier index on ties
        v   = cur ? v : vv;
        idx = cur ? idx : ii;
      }
      pa = v + fe + fs * (float)j + emc;
      inds[(t + 1) * 64 + j] = idx;
    }
    if (j == 63) sval = pa;
  }
  __syncthreads();
  if (tid == 0) {
    int ind = 63;
    for (int t = 127; t >= 0; --t) {
      ind = inds[t * 64 + ind];
      out[t] = (float)ind;
    }
    out[128] = sval;
  }
}

extern "C" void kernel_launch(void* const* d_in, const int* in_sizes, int n_in,
                              void* d_out, int out_size, void* d_ws, size_t ws_size,
                              hipStream_t stream) {
  const int*   x    = (const int*)d_in[0];
  const int*   y    = (const int*)d_in[1];
  const float* emb  = (const float*)d_in[2];
  const float* eWih = (const float*)d_in[3];
  const float* eWhh = (const float*)d_in[4];
  const float* ebih = (const float*)d_in[5];
  const float* ebhh = (const float*)d_in[6];
  const float* dWih = (const float*)d_in[7];
  const float* dWhh = (const float*)d_in[8];
  const float* dbih = (const float*)d_in[9];
  const float* dbhh = (const float*)d_in[10];
  const float* Weh  = (const float*)d_in[11];
  const float* beh  = (const float*)d_in[12];
  const float* Wem  = (const float*)d_in[13];
  const float* bem  = (const float*)d_in[14];
  float* ws  = (float*)d_ws;
  float* out = (float*)d_out;

  hipLaunchKernelGGL(kZero,     dim3(49),    dim3(256), 0, stream, ws);
  hipLaunchKernelGGL(kG0,       dim3(1528),  dim3(256), 0, stream, x, y, emb, eWih, ebih, ebhh, dWih, dbih, dbhh, ws);
  hipLaunchKernelGGL(kWemPrep,  dim3(16000), dim3(256), 0, stream, Wem, bem, ws);
  hipLaunchKernelGGL(kLstm,     dim3(1024),  dim3(512), 0, stream, eWhh, dWhh, ws);
  hipLaunchKernelGGL(kProj,     dim3(191),   dim3(256), 0, stream, Weh, beh, ws);
  hipLaunchKernelGGL(kLogits,   dim3(508),   dim3(256), 0, stream, ws);
  hipLaunchKernelGGL(kEmission, dim3(32),    dim3(256), 0, stream, y, Wem, ws);
  hipLaunchKernelGGL(kViterbi,  dim3(1),     dim3(256), 0, stream, ws, out);
}

// Round 7
// 593.833 us; speedup vs baseline: 1872.8013x; 3.9601x over previous
//
#include <hip/hip_runtime.h>

// Seq2SeqWithAlignment: enc/dec LSTM -> hpre -> logits logsumexp -> Viterbi align.
// K=64 enc steps, T=128 dec tokens (127 dec steps used), H=512, E=100, V=32000.

#define K_ENC 64
#define HID   512
#define EMB   100
#define VOC   32000
#define G4    2048   // 4*HID

typedef __attribute__((ext_vector_type(8))) short  short8;
typedef __attribute__((ext_vector_type(4))) float  f32x4;
typedef unsigned long long u64;

#define LOG2E 1.4426950408889634f
#define LN2   0.6931471805599453f

__device__ __forceinline__ unsigned short f2bf(float f) {
  union { float f; unsigned u; } x; x.f = f;
  unsigned r = x.u + 0x7FFFu + ((x.u >> 16) & 1u);  // RNE
  return (unsigned short)(r >> 16);
}

__device__ __forceinline__ float fast_sigmoid(float x) {
  return __builtin_amdgcn_rcpf(1.f + __builtin_amdgcn_exp2f(-LOG2E * x));
}
__device__ __forceinline__ float fast_tanh(float x) {
  return 1.f - 2.f * __builtin_amdgcn_rcpf(1.f + __builtin_amdgcn_exp2f(2.f * LOG2E * x));
}

// ---------------- workspace layout (float offsets) ----------------
// OFF_PAD (0..255): sync scratch (zeroed by kZero):
//   int idx 32: dec step counter (monotonic, +32 per step)
//   int idx 64: enc step counter      (128 B apart -> separate lines)
#define OFF_PAD   0
#define OFF_HBUF  256       // 2048 floats used: h slots [grp][2][512] (no tags)
#define OFF_G0E   4352      // 64*2048  : enc Wih@x + bih + bhh
#define OFF_G0D   135424    // 127*2048 : dec
#define OFF_EENC  395520    // 64*512
#define OFF_D     428288    // 127*512
#define OFF_EWE   493312    // 64*100   : log2e * Eenc@We_E^T
#define OFF_DWD   499712    // 127*100  : log2e * (D@We_D^T + beh)
#define OFF_BEM   512412    // 32000    : log2e * bem
#define OFF_SUM   544412    // 127*64   : sum of 2^s over v (atomic)
#define OFF_EM    552540    // 127*64   : emission
#define OFF_WEM   560668    // ushort[4096000]: Wem bf16 in MFMA-B fragment-linear layout
// total ~10.4 MB

// ---------------- zero init ----------------
__global__ void kZero(float* __restrict__ ws) {
  int gid = blockIdx.x * 256 + threadIdx.x;
  if (gid < 4352) ws[gid] = 0.f;                         // sync scratch + hbuf
  else if (gid < 4352 + 127 * 64) ws[OFF_SUM + gid - 4352] = 0.f;
}

// ---------------- G0 = Wih @ emb[tok] + bih + bhh ----------------
__global__ __launch_bounds__(256) void kG0(const int* __restrict__ x, const int* __restrict__ y,
                    const float* __restrict__ emb,
                    const float* __restrict__ eWih, const float* __restrict__ ebih,
                    const float* __restrict__ ebhh,
                    const float* __restrict__ dWih, const float* __restrict__ dbih,
                    const float* __restrict__ dbhh,
                    float* __restrict__ ws) {
  int gid = blockIdx.x * 256 + threadIdx.x;
  const int enc_total = K_ENC * G4;
  if (gid >= enc_total + 127 * G4) return;
  bool enc = gid < enc_total;
  int loc = enc ? gid : gid - enc_total;
  int t = loc >> 11, r = loc & (G4 - 1);
  int tok = enc ? x[t] : y[t];
  const float* Wr = (enc ? eWih : dWih) + r * EMB;
  const float* er = emb + tok * EMB;
  float s = 0.f;
  #pragma unroll 4
  for (int e = 0; e < EMB; ++e) s += er[e] * Wr[e];
  s += enc ? (ebih[r] + ebhh[r]) : (dbih[r] + dbhh[r]);
  ws[(enc ? OFF_G0E : OFF_G0D) + t * G4 + r] = s;
}

// ---------------- Wem -> bf16 MFMA-B fragment-linear layout, bem scaled ----------------
__global__ __launch_bounds__(256) void kWemPrep(const float* __restrict__ Wem,
                                               const float* __restrict__ bem,
                                               float* __restrict__ ws) {
  int gid = blockIdx.x * 256 + threadIdx.x;   // < 4096000
  int vt = gid >> 11;
  int kb = (gid >> 9) & 3;
  int L  = (gid >> 3) & 63;
  int j  = gid & 7;
  int v = vt * 16 + (L & 15);
  int k = kb * 32 + ((L >> 4) << 3) + j;
  float val = (k < EMB) ? Wem[v * EMB + k] : 0.f;
  ((unsigned short*)(ws + OFF_WEM))[gid] = f2bf(val);
  if (gid < VOC) ws[OFF_BEM + gid] = bem[gid] * LOG2E;
}

// ---------------- persistent LSTM: 64 WGs (32 dec + 32 enc), counter protocol ----------------
// R8 design (R6 post-mortem: sc0-only RMW polling causes L2 line ping-pong across
// CUs -> 27us/step + 300MB HBM writes; MALL RMWs don't migrate lines but the
// baseline polled 512 tagged words/WG/sweep = 16K in-flight RMWs of contention):
//   producers: 16 x global_store_dword sc0 sc1 (write-through to MALL, no RMW),
//              s_waitcnt vmcnt(0)  (stores MALL-ack'd),
//              __syncthreads, then ONE atomicAdd(cnt,1) per WG (MALL RMW).
//              Counter is MONOTONIC: after step t all WGs pushed it to 32*(t+1).
//   consumers: lane 0 polls ONE word (atomicOr(cnt,0), proven MALL primitive)
//              until cnt >= 32*t, then wave 0 reads the 512 floats with
//              global_load_dwordx4 sc0 sc1 (MALL reads: no RMW serialization,
//              bypass stale L1/L2 architecturally), stages into LDS.
// Ordering: store-ack -> barrier -> add; observer of add at MALL sees stores.
// Slot reuse safe: WG publishes h_{t+1} only after consuming h_t, and counter
// gating means slot t&1 is fully read by everyone before h_{t+2} overwrites it.
// Poll is BOUNDED: guard expiry => finite wrong answer, not a harness hang.
#define STEP_GUARD 16384

__global__ __launch_bounds__(512, 2) void kLstm(const float* __restrict__ eWhh,
                                                const float* __restrict__ dWhh,
                                                float* __restrict__ ws) {
  const int grp = blockIdx.x >> 5;            // 0=enc, 1=dec
  const int wg  = blockIdx.x & 31;
  const float* __restrict__ Whh = grp ? dWhh : eWhh;
  const float* __restrict__ G0  = ws + (grp ? OFF_G0D : OFF_G0E);
  float* hs = ws + (grp ? OFF_D : OFF_EENC);
  float* hb = ws + OFF_HBUF + grp * 1024;     // [2][512] floats
  int* cnt = (int*)ws + 32 + grp * 32;        // monotonic counter (zeroed)
  const int steps = grp ? 127 : K_ENC;
  const int tid = threadIdx.x;
  const int jl = tid >> 5, sub = tid & 31;
  const int j = wg * 16 + jl;                 // owned h index
  __shared__ float h_lds[32 * 20];            // [sub][16] padded to 20 (bank spread)

  // per-thread weight slice: 4 gates x 16 k (rows g*512+j, cols sub*16..+16)
  float4 w4[16];
  #pragma unroll
  for (int g = 0; g < 4; ++g)
    #pragma unroll
    for (int q = 0; q < 4; ++q)
      w4[g * 4 + q] = *(const float4*)&Whh[(g * HID + j) * HID + sub * 16 + q * 4];

  float cst = 0.f;
  for (int t = 0; t < steps; ++t) {
    // G0 loads are h-independent: issue before the poll so they overlap it
    float g0i = G0[t * G4 + j];
    float g0f = G0[t * G4 + HID + j];
    float g0g = G0[t * G4 + 2 * HID + j];
    float g0o = G0[t * G4 + 3 * HID + j];
    // ---- consume h_t: 1-word poll (lane 0) + vectorized MALL read (wave 0) ----
    int got = 0;
    if (tid == 0 && t > 0) {
      const int target = 32 * t;
      int guard = 0;
      for (;;) {
        got = atomicOr(cnt, 0);               // MALL RMW, single word
        if (got >= target || ++guard >= STEP_GUARD) break;
        __builtin_amdgcn_s_sleep(1);
      }
    }
    if (tid < 64) {
      const float* src = hb + (t & 1) * 512 + tid * 8;
      f32x4 a, b;
      // fake dep on 'got' orders the loads after the poll; volatile + wave
      // lockstep (lane0's loop masks the whole wave) enforce it anyway.
      asm volatile(
        "global_load_dwordx4 %0, %2, off sc0 sc1\n\t"
        "global_load_dwordx4 %1, %2, off offset:16 sc0 sc1\n\t"
        "s_waitcnt vmcnt(0)"
        : "=&v"(a), "=&v"(b)
        : "v"(src), "v"(got));
      #pragma unroll
      for (int i = 0; i < 8; ++i) {
        int k = tid * 8 + i;
        float v = (i < 4) ? a[i] : b[i - 4];
        h_lds[(k >> 4) * 20 + (k & 15)] = v;
      }
    }
    __syncthreads();
    float h[16];
    #pragma unroll
    for (int kk = 0; kk < 16; ++kk) h[kk] = h_lds[sub * 20 + kk];
    float p0 = 0.f, p1 = 0.f, p2 = 0.f, p3 = 0.f;
    #pragma unroll
    for (int q = 0; q < 4; ++q) {
      p0 += w4[0+q].x*h[q*4+0] + w4[0+q].y*h[q*4+1] + w4[0+q].z*h[q*4+2] + w4[0+q].w*h[q*4+3];
      p1 += w4[4+q].x*h[q*4+0] + w4[4+q].y*h[q*4+1] + w4[4+q].z*h[q*4+2] + w4[4+q].w*h[q*4+3];
      p2 += w4[8+q].x*h[q*4+0] + w4[8+q].y*h[q*4+1] + w4[8+q].z*h[q*4+2] + w4[8+q].w*h[q*4+3];
      p3 += w4[12+q].x*h[q*4+0] + w4[12+q].y*h[q*4+1] + w4[12+q].z*h[q*4+2] + w4[12+q].w*h[q*4+3];
    }
    #pragma unroll
    for (int d = 1; d <= 16; d <<= 1) {       // reduce over 32 sub-lanes (stays in 32-half)
      p0 += __shfl_xor(p0, d); p1 += __shfl_xor(p1, d);
      p2 += __shfl_xor(p2, d); p3 += __shfl_xor(p3, d);
    }
    float si = fast_sigmoid(g0i + p0);
    float sf = fast_sigmoid(g0f + p1);
    float gG = fast_tanh(g0g + p2);
    float so = fast_sigmoid(g0o + p3);
    cst = sf * cst + si * gG;
    float hn = so * fast_tanh(cst);
    // ---- publish h_{t+1}: MALL write-through stores, ack, barrier, 1 add ----
    if (sub == 0) {
      float* dst = hb + ((t + 1) & 1) * 512 + j;
      asm volatile(
        "global_store_dword %0, %1, off sc0 sc1\n\t"
        "s_waitcnt vmcnt(0)"
        : : "v"(dst), "v"(hn));
      hs[t * HID + j] = hn;
    }
    __syncthreads();                          // all 16 publishes MALL-ack'd
    if (tid == 0) atomicAdd(cnt, 1);          // MALL RMW: step complete marker
  }
}

// ---------------- EWe_s / DWd_s projections (scaled by log2e) ----------------
__global__ __launch_bounds__(256) void kProj(const float* __restrict__ Weh,
                                             const float* __restrict__ beh,
                                             float* __restrict__ ws) {
  int bid = blockIdx.x;                 // 0..190
  bool enc = bid < K_ENC;
  int row = enc ? bid : bid - K_ENC;
  const float* in = ws + (enc ? OFF_EENC : OFF_D) + row * HID;
  __shared__ float sin_[HID];
  int tid = threadIdx.x;
  sin_[tid] = in[tid]; sin_[tid + 256] = in[tid + 256];
  __syncthreads();
  if (tid < EMB) {
    const float* wr = Weh + tid * 1024 + (enc ? 0 : HID);
    float s = 0.f;
    #pragma unroll 4
    for (int h = 0; h < HID; ++h) s += sin_[h] * wr[h];
    if (!enc) s += beh[tid];
    ws[(enc ? OFF_EWE : OFF_DWD) + row * EMB + tid] = s * LOG2E;
  }
}

// ---------------- fused logits GEMM (bf16 MFMA) + online sum(2^s) ----------------
__global__ __launch_bounds__(256) void kLogits(float* __restrict__ ws) {
  const int t = blockIdx.x >> 2;
  const int chunk = blockIdx.x & 3;
  const int tid = threadIdx.x;
  const int lane = tid & 63;
  const int wv = tid >> 6;
  const int quad = lane >> 4, l15 = lane & 15;
  __shared__ __align__(16) unsigned short A[64 * 128];   // hpre_s bf16, [m][k] k-padded to 128
  const float* EWe = ws + OFF_EWE;
  const float* DWd = ws + OFF_DWD + t * EMB;
  for (int idx = tid; idx < 64 * 128; idx += 256) {
    int m = idx >> 7, k = idx & 127;
    float hv = 0.f;
    if (k < EMB) { float s = EWe[m * EMB + k] + DWd[k]; hv = s > 0.f ? s : 0.f; }
    A[idx] = f2bf(hv);
  }
  __syncthreads();
  short8 af[4][4];   // A fragments persistent in VGPRs: [mtile][kblock]
  #pragma unroll
  for (int mt = 0; mt < 4; ++mt)
    #pragma unroll
    for (int kb = 0; kb < 4; ++kb)
      af[mt][kb] = *(const short8*)&A[(mt * 16 + l15) * 128 + kb * 32 + quad * 8];
  const unsigned short* wem = (const unsigned short*)(ws + OFF_WEM);
  const float* bem_s = ws + OFF_BEM;
  float rs[4][4];
  #pragma unroll
  for (int a = 0; a < 4; ++a)
    #pragma unroll
    for (int b = 0; b < 4; ++b) rs[a][b] = 0.f;
  int vt = chunk * 500 + wv;
  short8 nb0, nb1, nb2, nb3; float nbi;
  nb0 = *(const short8*)&wem[(vt * 4 + 0) * 512 + lane * 8];
  nb1 = *(const short8*)&wem[(vt * 4 + 1) * 512 + lane * 8];
  nb2 = *(const short8*)&wem[(vt * 4 + 2) * 512 + lane * 8];
  nb3 = *(const short8*)&wem[(vt * 4 + 3) * 512 + lane * 8];
  nbi = bem_s[vt * 16 + l15];
  for (int ii = wv; ii < 500; ii += 4) {
    short8 cb0 = nb0, cb1 = nb1, cb2 = nb2, cb3 = nb3;
    float cbi = nbi;
    int nvt = vt + 4;
    if (ii + 4 < 500) {   // software pipeline next B tile
      nb0 = *(const short8*)&wem[(nvt * 4 + 0) * 512 + lane * 8];
      nb1 = *(const short8*)&wem[(nvt * 4 + 1) * 512 + lane * 8];
      nb2 = *(const short8*)&wem[(nvt * 4 + 2) * 512 + lane * 8];
      nb3 = *(const short8*)&wem[(nvt * 4 + 3) * 512 + lane * 8];
      nbi = bem_s[nvt * 16 + l15];
    }
    f32x4 acc[4];
    #pragma unroll
    for (int mt = 0; mt < 4; ++mt) acc[mt] = (f32x4){cbi, cbi, cbi, cbi};  // init with bem
    #pragma unroll
    for (int mt = 0; mt < 4; ++mt) {
      acc[mt] = __builtin_amdgcn_mfma_f32_16x16x32_bf16(af[mt][0], cb0, acc[mt], 0, 0, 0);
      acc[mt] = __builtin_amdgcn_mfma_f32_16x16x32_bf16(af[mt][1], cb1, acc[mt], 0, 0, 0);
      acc[mt] = __builtin_amdgcn_mfma_f32_16x16x32_bf16(af[mt][2], cb2, acc[mt], 0, 0, 0);
      acc[mt] = __builtin_amdgcn_mfma_f32_16x16x32_bf16(af[mt][3], cb3, acc[mt], 0, 0, 0);
    }
    #pragma unroll
    for (int mt = 0; mt < 4; ++mt)
      #pragma unroll
      for (int r = 0; r < 4; ++r)
        rs[mt][r] += __builtin_amdgcn_exp2f(acc[mt][r]);   // s already includes log2e scale
    vt = nvt;
  }
  // reduce across the 16 column-lanes of each quad, then one atomic per row
  #pragma unroll
  for (int d = 1; d < 16; d <<= 1)
    #pragma unroll
    for (int mt = 0; mt < 4; ++mt)
      #pragma unroll
      for (int r = 0; r < 4; ++r)
        rs[mt][r] += __shfl_xor(rs[mt][r], d);
  if (l15 == 0) {
    float* sum = ws + OFF_SUM + t * 64;
    #pragma unroll
    for (int mt = 0; mt < 4; ++mt)
      #pragma unroll
      for (int r = 0; r < 4; ++r)
        atomicAdd(&sum[mt * 16 + quad * 4 + r], rs[mt][r]);
  }
}

// ---------------- emission = ln2 * (s_word - log2(sum 2^s)), s_word in fp32 ----------------
__global__ __launch_bounds__(256) void kEmission(const int* __restrict__ y,
                                                 const float* __restrict__ Wem,
                                                 float* __restrict__ ws) {
  int gid = blockIdx.x * 256 + threadIdx.x;
  if (gid >= 127 * 64) return;
  int t = gid >> 6, m = gid & 63;
  const float* ew = ws + OFF_EWE + m * EMB;
  const float* dw = ws + OFF_DWD + t * EMB;
  int wt = y[t + 1];
  const float* wr = Wem + wt * EMB;
  float s = ws[OFF_BEM + wt];
  #pragma unroll 4
  for (int e = 0; e < EMB; ++e) {
    float h = ew[e] + dw[e];
    h = h > 0.f ? h : 0.f;
    s += h * wr[e];
  }
  ws[OFF_EM + gid] = LN2 * (s - __builtin_amdgcn_logf(ws[OFF_SUM + gid]));
}

// ---------------- Viterbi: prefix-max trick + backtrace ----------------
__global__ __launch_bounds__(256) void kViterbi(const float* __restrict__ ws, float* __restrict__ out) {
  __shared__ float em_lds[127 * 64];
  __shared__ int   inds[128 * 64];
  __shared__ float sval;
  const int tid = threadIdx.x;
  for (int i = tid; i < 127 * 64; i += 256) em_lds[i] = ws[OFF_EM + i];
  if (tid < 64) inds[tid] = 0;   // indices row 0
  __syncthreads();
  if (tid < 64) {
    const int j = tid;
    const float fs = -0.4054651081081644f;   // log(128/192)
    const float fe = -1.0986122886681098f;   // log(64/192)
    float pa = 0.f;
    float emnext = em_lds[j];
    for (int t = 0; t < 127; ++t) {
      float emc = emnext;
      if (t < 126) emnext = em_lds[(t + 1) * 64 + j];
      float v = fmaf(-fs, (float)j, pa);   // q[j]
      int idx = j;
      #pragma unroll
      for (int d = 1; d < 64; d <<= 1) {   // inclusive prefix max, earliest argmax on ties
        float vv = __shfl_up(v, d);
        int   ii = __shfl_up(idx, d);
        bool cur = v > vv;                 // strict >: keep earlier index on ties
        v   = cur ? v : vv;
        idx = cur ? idx : ii;
      }
      pa = v + fe + fs * (float)j + emc;
      inds[(t + 1) * 64 + j] = idx;
    }
    if (j == 63) sval = pa;
  }
  __syncthreads();
  if (tid == 0) {
    int ind = 63;
    for (int t = 127; t >= 0; --t) {
      ind = inds[t * 64 + ind];
      out[t] = (float)ind;
    }
    out[128] = sval;
  }
}

extern "C" void kernel_launch(void* const* d_in, const int* in_sizes, int n_in,
                              void* d_out, int out_size, void* d_ws, size_t ws_size,
                              hipStream_t stream) {
  const int*   x    = (const int*)d_in[0];
  const int*   y    = (const int*)d_in[1];
  const float* emb  = (const float*)d_in[2];
  const float* eWih = (const float*)d_in[3];
  const float* eWhh = (const float*)d_in[4];
  const float* ebih = (const float*)d_in[5];
  const float* ebhh = (const float*)d_in[6];
  const float* dWih = (const float*)d_in[7];
  const float* dWhh = (const float*)d_in[8];
  const float* dbih = (const float*)d_in[9];
  const float* dbhh = (const float*)d_in[10];
  const float* Weh  = (const float*)d_in[11];
  const float* beh  = (const float*)d_in[12];
  const float* Wem  = (const float*)d_in[13];
  const float* bem  = (const float*)d_in[14];
  float* ws  = (float*)d_ws;
  float* out = (float*)d_out;

  hipLaunchKernelGGL(kZero,     dim3(49),    dim3(256), 0, stream, ws);
  hipLaunchKernelGGL(kG0,       dim3(1528),  dim3(256), 0, stream, x, y, emb, eWih, ebih, ebhh, dWih, dbih, dbhh, ws);
  hipLaunchKernelGGL(kWemPrep,  dim3(16000), dim3(256), 0, stream, Wem, bem, ws);
  hipLaunchKernelGGL(kLstm,     dim3(64),    dim3(512), 0, stream, eWhh, dWhh, ws);
  hipLaunchKernelGGL(kProj,     dim3(191),   dim3(256), 0, stream, Weh, beh, ws);
  hipLaunchKernelGGL(kLogits,   dim3(508),   dim3(256), 0, stream, ws);
  hipLaunchKernelGGL(kEmission, dim3(32),    dim3(256), 0, stream, y, Wem, ws);
  hipLaunchKernelGGL(kViterbi,  dim3(1),     dim3(256), 0, stream, ws, out);
}